// Round 12
// baseline (592.135 us; speedup 1.0000x reference)
//
#include <hip/hip_runtime.h>

#define T_LEN 2048
#define HID   25
#define LOG2E 1.4426950408889634f

// may_alias vectors for the LDS h-row readback (written as scalar float):
// without may_alias, TBAA licenses hoisting the reads above the publish
// (the R3/R7 corruption).
typedef float vf4 __attribute__((vector_size(16), may_alias));
typedef float vf2 __attribute__((vector_size(8),  may_alias));
typedef float f2  __attribute__((ext_vector_type(2)));

__device__ __forceinline__ float fast_rcp(float x) { return __builtin_amdgcn_rcpf(x); }
__device__ __forceinline__ float fast_exp2(float x) { return __builtin_amdgcn_exp2f(x); }

// R12 = R11 (545 us champion) + per-step in-register y + single fence.
// One chain per 32-lane half-wave; lane u owns ALL FOUR gate rows of unit u.
// 1024 waves = 1 wave/SIMD; amdgpu_waves_per_eu(1,1) -> full VGPR budget,
// no AGPR demotion (R8 lesson). h exchange via interleaved LDS broadcast row
// [h0,h12,h1,h13,...,h11,h23,h24,0,...]: the b128/b64 readback yields
// register-aligned (h_k, h_{k+12}) pairs feeding v_pk_fma_f32 directly.
// Junk lanes (u>=25) publish to a dump row so slot 25 stays 0 and
// (h24, 0) is a clean b64 pair for the 13th pk.
// y_t = h_t . w_dense is computed per step IN REGISTER (13 pk + add):
// independent of the recurrence critical path, it fills the ~213 cyc/step
// of exposed LDS-roundtrip + trans-chain latency measured in R11, and
// removes the hist ds_write + the bursty 32-step y-batch.
// sigmoid/tanh in exp2 domain (weights pre-scaled by -log2e / +2log2e).
// absmax has sat at exactly 2^-9 across five summation orders (harness
// comparison floor) -> ulp-level regrouping here is safe.

__global__ __attribute__((amdgpu_flat_work_group_size(256, 256),
                          amdgpu_waves_per_eu(1, 1)))
void lstm_fused(
    const float* __restrict__ x,        // [B, T, 1]
    const float* __restrict__ w_ih,     // [100, 1]
    const float* __restrict__ w_hh,     // [100, 25]
    const float* __restrict__ b_ih,     // [100]
    const float* __restrict__ b_hh,     // [100]
    const float* __restrict__ w_dense,  // [1, 25]
    const float* __restrict__ b_dense,  // [1]
    float* __restrict__ out)            // [B, T, 1]
{
    const int tid  = threadIdx.x;
    const int u    = tid & 31;           // hidden unit / y-slot owned by lane
    const int cb   = tid >> 5;           // chain index in block, 0..7
    const int b    = blockIdx.x * 8 + cb;
    const bool act = u < HID;

    // rows 0..7: interleaved h rows per chain; rows 8..15: junk-lane dump.
    __shared__ __align__(16) float hbuf[16][32];

    const float si = -LOG2E, sg = 2.f * LOG2E;

    // ---- recurrent weights as (k, k+12) pairs + (w24, 0), exp2 domain ----
    f2 wI2[13], wF2[13], wG2[13], wO2[13];
#pragma unroll
    for (int m = 0; m < 12; ++m) {
        wI2[m] = act ? f2{si * w_hh[u * HID + m],             si * w_hh[u * HID + m + 12]}             : f2{0.f, 0.f};
        wF2[m] = act ? f2{si * w_hh[(HID + u) * HID + m],     si * w_hh[(HID + u) * HID + m + 12]}     : f2{0.f, 0.f};
        wG2[m] = act ? f2{sg * w_hh[(2 * HID + u) * HID + m], sg * w_hh[(2 * HID + u) * HID + m + 12]} : f2{0.f, 0.f};
        wO2[m] = act ? f2{si * w_hh[(3 * HID + u) * HID + m], si * w_hh[(3 * HID + u) * HID + m + 12]} : f2{0.f, 0.f};
    }
    wI2[12] = act ? f2{si * w_hh[u * HID + 24], 0.f}             : f2{0.f, 0.f};
    wF2[12] = act ? f2{si * w_hh[(HID + u) * HID + 24], 0.f}     : f2{0.f, 0.f};
    wG2[12] = act ? f2{sg * w_hh[(2 * HID + u) * HID + 24], 0.f} : f2{0.f, 0.f};
    wO2[12] = act ? f2{si * w_hh[(3 * HID + u) * HID + 24], 0.f} : f2{0.f, 0.f};

    const float bI  = act ? si * (b_ih[u] + b_hh[u]) : 0.f;
    const float bF  = act ? si * (b_ih[HID + u] + b_hh[HID + u]) : 0.f;
    const float bG  = act ? sg * (b_ih[2 * HID + u] + b_hh[2 * HID + u]) : 0.f;
    const float bO  = act ? si * (b_ih[3 * HID + u] + b_hh[3 * HID + u]) : 0.f;
    const float wxI = act ? si * w_ih[u] : 0.f;
    const float wxF = act ? si * w_ih[HID + u] : 0.f;
    const float wxG = act ? sg * w_ih[2 * HID + u] : 0.f;
    const float wxO = act ? si * w_ih[3 * HID + u] : 0.f;
    const float bd  = b_dense[0];

    // dense weights as (m, m+12) pairs + (wd24, 0) -- wave-uniform (SGPRs)
    f2 wd2[13];
#pragma unroll
    for (int m = 0; m < 12; ++m) wd2[m] = f2{w_dense[m], w_dense[m + 12]};
    wd2[12] = f2{w_dense[24], 0.f};

    // h0 = 0 everywhere (incl. the permanently-zero slot 25 and dump rows)
    hbuf[cb][u] = 0.f;
    hbuf[8 + cb][u] = 0.f;

    // interleaved publish slot (bijection 0..24); junk lanes -> dump row.
    // Pointer is loop-invariant: unconditional ds_write, no exec-mask dance.
    const int slot = (u < 12) ? 2 * u : (u < 24) ? 2 * u - 23 : 24;
    float* hwr = act ? &hbuf[cb][slot] : &hbuf[8 + cb][u];
    const vf4* r4 = (const vf4*)&hbuf[cb][0];
    const vf2* r2 = (const vf2*)&hbuf[cb][24];   // (h24, 0)

    const float4* __restrict__ xp = (const float4*)(x + (size_t)b * T_LEN);
    float* __restrict__ orow = out + (size_t)b * T_LEN;

    // h state as 13 register-aligned pairs (h_m, h_{m+12}), hp[12]=(h24,0)
    f2 hp[13];
#pragma unroll
    for (int m = 0; m < 13; ++m) hp[m] = f2{0.f, 0.f};

    float c = 0.f;
    float yroll = 0.f;
    float4 xcur = xp[0];

    for (int it = 0; it < T_LEN / 4; ++it) {
        const int nx = (it + 1 < T_LEN / 4) ? it + 1 : it;
        float4 xnext = xp[nx];  // issued ~4 steps ahead of use
        float xs[4] = {xcur.x, xcur.y, xcur.z, xcur.w};

#pragma unroll
        for (int s = 0; s < 4; ++s) {
            const float xv = xs[s];
            const int t = 4 * it + s;

            // four gate pre-activations via v_pk_fma_f32 (13 pk each; the
            // 13th pair is (h24,0)x(w24,0)); final horizontal add.
            f2 accI = f2{fmaf(xv, wxI, bI), 0.f};
            f2 accF = f2{fmaf(xv, wxF, bF), 0.f};
            f2 accG = f2{fmaf(xv, wxG, bG), 0.f};
            f2 accO = f2{fmaf(xv, wxO, bO), 0.f};
#pragma unroll
            for (int m = 0; m < 13; ++m) {
                const f2 h = hp[m];
                accI = __builtin_elementwise_fma(h, wI2[m], accI);
                accF = __builtin_elementwise_fma(h, wF2[m], accF);
                accG = __builtin_elementwise_fma(h, wG2[m], accG);
                accO = __builtin_elementwise_fma(h, wO2[m], accO);
            }
            const float aI = accI.x + accI.y;
            const float aF = accF.x + accF.y;
            const float aG = accG.x + accG.y;
            const float aO = accO.x + accO.y;

            const float sI = fast_rcp(1.f + fast_exp2(aI));          // sig(i)
            const float sF = fast_rcp(1.f + fast_exp2(aF));          // sig(f)
            const float sO = fast_rcp(1.f + fast_exp2(aO));          // sig(o)
            const float tG = fmaf(-2.f, fast_rcp(1.f + fast_exp2(aG)), 1.f); // tanh(g)

            c = fmaf(sF, c, sI * tG);
            const float tC = fmaf(-2.f, fast_rcp(1.f + fast_exp2(2.f * LOG2E * c)), 1.f);
            const float hn = sO * tC;

            // ---- ordered publish -> readback (single fence; the next
            // step's publish is ordered by data deps through hp) ----
            *hwr = hn;
            __asm__ __volatile__("" ::: "memory");
            {
                vf4 a0 = r4[0], a1 = r4[1], a2 = r4[2];
                vf4 a3 = r4[3], a4 = r4[4], a5 = r4[5];
                vf2 a6 = r2[0];                       // (h24, 0)
                hp[0]  = f2{a0[0], a0[1]}; hp[1]  = f2{a0[2], a0[3]};
                hp[2]  = f2{a1[0], a1[1]}; hp[3]  = f2{a1[2], a1[3]};
                hp[4]  = f2{a2[0], a2[1]}; hp[5]  = f2{a2[2], a2[3]};
                hp[6]  = f2{a3[0], a3[1]}; hp[7]  = f2{a3[2], a3[3]};
                hp[8]  = f2{a4[0], a4[1]}; hp[9]  = f2{a4[2], a4[3]};
                hp[10] = f2{a5[0], a5[1]}; hp[11] = f2{a5[2], a5[3]};
                hp[12] = f2{a6[0], a6[1]};
            }

            // per-step y in register: independent of the recurrence critical
            // path -> fills the LDS/trans latency shadow. Lane u keeps step
            // t0+u's value; coalesced 128 B store every 32 steps.
            {
                f2 accY = f2{0.f, 0.f};
#pragma unroll
                for (int m = 0; m < 13; ++m)
                    accY = __builtin_elementwise_fma(hp[m], wd2[m], accY);
                const float ys = accY.x + accY.y;
                yroll = ((t & 31) == u) ? ys : yroll;
                if ((t & 31) == 31)
                    orow[(t & ~31) + u] = yroll + bd;
            }
        }
        xcur = xnext;
    }
}

extern "C" void kernel_launch(void* const* d_in, const int* in_sizes, int n_in,
                              void* d_out, int out_size, void* d_ws, size_t ws_size,
                              hipStream_t stream) {
    const float* x       = (const float*)d_in[0];
    const float* w_ih    = (const float*)d_in[1];
    const float* w_hh    = (const float*)d_in[2];
    const float* b_ih    = (const float*)d_in[3];
    const float* b_hh    = (const float*)d_in[4];
    const float* w_dense = (const float*)d_in[5];
    const float* b_dense = (const float*)d_in[6];
    float* out = (float*)d_out;

    // 2048 chains, one per 32-lane half-wave: 256 blocks x 256 threads
    // -> 1024 waves = 1 wave/SIMD chip-wide, 4 waves/CU.
    lstm_fused<<<dim3(256), dim3(256), 0, stream>>>(x, w_ih, w_hh, b_ih, b_hh,
                                                    w_dense, b_dense, out);
}